// Round 2
// baseline (20537.511 us; speedup 1.0000x reference)
//
#include <hip/hip_runtime.h>

// ---------------------------------------------------------------------------
// RNN_Layer: x[B,T,C] fp32 -> conv1x1(w_in) -> dense(kernel) -> LSTM(rec)
//            -> dense(w_out).  B=32 T=1024 C=512 D=256 U=256 O=256.
// All inputs/outputs fp32 (per reference). GEMMs: bf16 MFMA with in-register
// fp32->bf16 conversion, fp32 accumulate. LSTM: one WG per batch, rec_kernel
// pre-converted to bf16 (512KB) streamed from L2 each step (~3.6us/step/CU
// structural floor for the no-sync design).
// ---------------------------------------------------------------------------

#define DEV static __device__ __forceinline__

typedef __attribute__((ext_vector_type(8))) short short8;
typedef __attribute__((ext_vector_type(4))) float floatx4;

static constexpr int Bsz = 32, T = 1024, C = 512, D = 256, U = 256, FU = 1024;
static constexpr int M = Bsz * T;   // 32768 rows for all GEMMs

DEV float bfu2f(unsigned int u) { union { unsigned int i; float f; } v; v.i = u; return v.f; }
DEV float bf2f(unsigned short u) { return bfu2f(((unsigned int)u) << 16); }
DEV unsigned short f2bf(float f) {
    union { float f; unsigned int i; } v; v.f = f;
    return (unsigned short)((v.i + 0x7fffu + ((v.i >> 16) & 1u)) >> 16);
}
DEV float sigmf(float x) { return 1.0f / (1.0f + __expf(-x)); }
DEV float rdlane(float v, int l) {
    return __builtin_bit_cast(float, __builtin_amdgcn_readlane(__builtin_bit_cast(int, v), l));
}

// fp32-or-bf16 element -> bf16 bit pattern
DEV short ld_bf(const float* p) { return (short)f2bf(*p); }
DEV short ld_bf(const unsigned short* p) { return (short)*p; }
// 8 consecutive elements -> bf16 A/B fragment
DEV short8 ld_frag(const unsigned short* p) { return *(const short8*)p; }
DEV short8 ld_frag(const float* p) {
    short8 v;
#pragma unroll
    for (int j = 0; j < 8; j++) v[j] = (short)f2bf(p[j]);
    return v;
}

// ---------------------------------------------------------------------------
// Fragment-direct MFMA GEMM:  C[M,N] = A[M,K] @ B[K,N] + bias[N]
// One wave/block. Wave owns NS 16-col strips (B frags in VGPRs for whole K),
// iterates MT 16-row tiles. Layouts (m89/m120-verified):
//   A[m=lane&15][k=quad*8+j]; B[k=quad*8+j][n=lane&15]; D[m=quad*4+r][n=lane&15]
// ---------------------------------------------------------------------------
template <int K, int N, int MT, int NS, bool OUTF32, typename AT, typename BT>
__global__ __launch_bounds__(64) void gemm_mfma(
    const AT* __restrict__ A,
    const BT* __restrict__ Bm,
    const float* __restrict__ bias,
    void* __restrict__ Cv)
{
    constexpr int KC = K / 32;
    const int lane = threadIdx.x;
    const int quad = lane >> 4, lr = lane & 15;
    constexpr int NSG = N / (16 * NS);
    const int sg = blockIdx.x % NSG;
    const int mb = blockIdx.x / NSG;
    const int n0 = sg * 16 * NS;

    short8 bf[NS][KC];
    float biasv[NS];
#pragma unroll
    for (int s = 0; s < NS; s++) {
        const int n = n0 + s * 16 + lr;
        biasv[s] = bias[n];
#pragma unroll
        for (int kc = 0; kc < KC; kc++) {
            short8 v;
#pragma unroll
            for (int j = 0; j < 8; j++) {
                const int k = kc * 32 + quad * 8 + j;
                v[j] = ld_bf(&Bm[(size_t)k * N + n]);
            }
            bf[s][kc] = v;
        }
    }

    for (int mt = 0; mt < MT; mt++) {
        const int m0 = (mb * MT + mt) * 16;
        const AT* Ap = A + (size_t)(m0 + lr) * K + quad * 8;
        floatx4 acc[NS];
#pragma unroll
        for (int s = 0; s < NS; s++) acc[s] = (floatx4){0.f, 0.f, 0.f, 0.f};
#pragma unroll
        for (int kc = 0; kc < KC; kc++) {
            short8 af = ld_frag(Ap + kc * 32);
#pragma unroll
            for (int s = 0; s < NS; s++)
                acc[s] = __builtin_amdgcn_mfma_f32_16x16x32_bf16(af, bf[s][kc], acc[s], 0, 0, 0);
        }
#pragma unroll
        for (int s = 0; s < NS; s++) {
            const int n = n0 + s * 16 + lr;
#pragma unroll
            for (int r = 0; r < 4; r++) {
                const int m = m0 + quad * 4 + r;
                const float val = acc[s][r] + biasv[s];
                if (OUTF32)
                    ((float*)Cv)[(size_t)m * N + n] = val;
                else
                    ((unsigned short*)Cv)[(size_t)m * N + n] = f2bf(val);
            }
        }
    }
}

// fp32 -> bf16 conversion (for rec_kernel)
__global__ __launch_bounds__(256) void cvt_bf16(const float* __restrict__ in,
                                                unsigned short* __restrict__ out, int n) {
    const int i = blockIdx.x * 256 + threadIdx.x;
    if (i < n) out[i] = f2bf(in[i]);
}

// ---------------------------------------------------------------------------
// LSTM: one WG (512 threads) per batch element. Thread owns columns 2t,2t+1
// of the [256,1024] rec matmul (packed-uint bf16 loads). h broadcast via
// v_readlane from a per-wave float4 (keeps the hot loop off the LDS pipe).
// Gate order (Keras): i, f, g, o.  Cell math in fp32.
// ---------------------------------------------------------------------------
DEV void loadpair(const float* p, float& z0, float& z1) {
    const float2 v = *(const float2*)p;
    z0 = v.x; z1 = v.y;
}
DEV void loadpair(const unsigned short* p, float& z0, float& z1) {
    const unsigned int w = *(const unsigned int*)p;
    z0 = bfu2f(w << 16); z1 = bfu2f(w & 0xffff0000u);
}

template <typename XZT>
__global__ __launch_bounds__(512) void lstm_kernel(
    const XZT* __restrict__ xz,            // [B, T, 4U]
    const unsigned int* __restrict__ W2,   // rec bf16 [U][FU] viewed as uint pairs
    unsigned short* __restrict__ hs)       // [B, T, U] bf16 out
{
    const int b = blockIdx.x;
    const int tid = threadIdx.x;
    const int lane = tid & 63;
    const int c0 = tid * 2;
    __shared__ float h_sh[U];
    __shared__ float z_sh[FU];
    float c = 0.f;
    if (tid < U) h_sh[tid] = 0.f;
    __syncthreads();

    const XZT* xzb = xz + (size_t)b * T * FU;
    unsigned short* hsb = hs + (size_t)b * T * U;

    for (int t = 0; t < T; t++) {
        // h into per-wave registers: lane l holds h[4l..4l+3]
        const float4 hr = *(const float4*)&h_sh[lane * 4];
        float z0, z1;
        loadpair(xzb + (size_t)t * FU + c0, z0, z1);
#pragma unroll
        for (int l = 0; l < 64; l++) {
            const float a0 = rdlane(hr.x, l);
            const float a1 = rdlane(hr.y, l);
            const float a2 = rdlane(hr.z, l);
            const float a3 = rdlane(hr.w, l);
            const unsigned int w0 = W2[(size_t)(4 * l + 0) * (FU / 2) + tid];
            const unsigned int w1 = W2[(size_t)(4 * l + 1) * (FU / 2) + tid];
            const unsigned int w2 = W2[(size_t)(4 * l + 2) * (FU / 2) + tid];
            const unsigned int w3 = W2[(size_t)(4 * l + 3) * (FU / 2) + tid];
            z0 += a0 * bfu2f(w0 << 16); z1 += a0 * bfu2f(w0 & 0xffff0000u);
            z0 += a1 * bfu2f(w1 << 16); z1 += a1 * bfu2f(w1 & 0xffff0000u);
            z0 += a2 * bfu2f(w2 << 16); z1 += a2 * bfu2f(w2 & 0xffff0000u);
            z0 += a3 * bfu2f(w3 << 16); z1 += a3 * bfu2f(w3 & 0xffff0000u);
        }
        z_sh[c0] = z0;
        z_sh[c0 + 1] = z1;
        __syncthreads();
        if (tid < U) {
            const float iv = sigmf(z_sh[tid]);
            const float fv = sigmf(z_sh[tid + U]);
            const float gv = tanhf(z_sh[tid + 2 * U]);
            const float ov = sigmf(z_sh[tid + 3 * U]);
            c = fv * c + iv * gv;
            const float hv = ov * tanhf(c);
            h_sh[tid] = hv;
            hsb[(size_t)t * U + tid] = f2bf(hv);
        }
        __syncthreads();
    }
}

// ---------------------------------------------------------------------------
extern "C" void kernel_launch(void* const* d_in, const int* in_sizes, int n_in,
                              void* d_out, int out_size, void* d_ws, size_t ws_size,
                              hipStream_t stream)
{
    const float* x    = (const float*)d_in[0];
    const float* w_in = (const float*)d_in[1];
    const float* b_in = (const float*)d_in[2];
    const float* kern = (const float*)d_in[3];
    const float* rec  = (const float*)d_in[4];
    const float* bias = (const float*)d_in[5];
    const float* wout = (const float*)d_in[6];
    const float* bout = (const float*)d_in[7];

    char* ws = (char*)d_ws;
    const size_t rec_bytes = (size_t)U * FU * 2;          // 512 KiB
    const size_t xin_bytes = (size_t)M * D * 2;           // 16 MiB
    const size_t hs_bytes  = (size_t)M * U * 2;           // 16 MiB
    const size_t xz32_bytes = (size_t)M * FU * 4;         // 128 MiB
    const size_t base = rec_bytes + xin_bytes + hs_bytes;

    unsigned short* rec_bf = (unsigned short*)ws;
    unsigned short* xin_bf = (unsigned short*)(ws + rec_bytes);
    unsigned short* hs_bf  = (unsigned short*)(ws + rec_bytes + xin_bytes);
    char* xz_raw = ws + base;

    const bool use_f32 = ws_size >= base + xz32_bytes;

    // rec_kernel fp32 -> bf16 (halves the per-step L2 stream in the LSTM)
    cvt_bf16<<<(U * FU) / 256, 256, 0, stream>>>(rec, rec_bf, U * FU);

    // GEMM1: xin = bf16(x @ w_in + b_in)   [M,512]x[512,256]
    gemm_mfma<512, 256, 16, 2, false><<<(256 / 32) * (M / 256), 64, 0, stream>>>(
        x, w_in, b_in, (void*)xin_bf);

    if (use_f32) {
        float* xz = (float*)xz_raw;
        // GEMM2: xz = fp32(xin @ kernel + bias)  [M,256]x[256,1024]
        gemm_mfma<256, 1024, 16, 2, true><<<(1024 / 32) * (M / 256), 64, 0, stream>>>(
            xin_bf, kern, bias, (void*)xz);
        lstm_kernel<float><<<Bsz, 512, 0, stream>>>(xz, (const unsigned int*)rec_bf, hs_bf);
    } else {
        unsigned short* xz = (unsigned short*)xz_raw;
        gemm_mfma<256, 1024, 16, 2, false><<<(1024 / 32) * (M / 256), 64, 0, stream>>>(
            xin_bf, kern, bias, (void*)xz);
        lstm_kernel<unsigned short><<<Bsz, 512, 0, stream>>>(xz, (const unsigned int*)rec_bf, hs_bf);
    }

    // GEMM3: out = fp32(hs @ w_out + b_out)  [M,256]x[256,256]
    gemm_mfma<256, 256, 16, 2, true><<<(256 / 32) * (M / 256), 64, 0, stream>>>(
        hs_bf, wout, bout, d_out);
}

// Round 3
// 17376.042 us; speedup vs baseline: 1.1819x; 1.1819x over previous
//
#include <hip/hip_runtime.h>

// ---------------------------------------------------------------------------
// RNN_Layer: x[B,T,C] fp32 -> conv1x1(w_in) -> dense(kernel) -> LSTM(rec)
//            -> dense(w_out).  B=32 T=1024 C=512 D=256 U=256 O=256.
// R2: LSTM rebuilt for L2 bandwidth: W packed to [64][512][4-row uint4],
// dwordx4 streaming with 4-deep prefetch, readlane h-broadcast, float2
// accumulators (pk_fma), XCD-staggered chunk order, xz step-ahead prefetch.
// Floor: max(512KB/step @64B/clk/CU = 3.4us, VALU ~1.8us) -> ~4.5ms LSTM.
// ---------------------------------------------------------------------------

#define DEV static __device__ __forceinline__

typedef __attribute__((ext_vector_type(8))) short short8;
typedef __attribute__((ext_vector_type(4))) float floatx4;
typedef __attribute__((ext_vector_type(2))) float floatx2;

static constexpr int Bsz = 32, T = 1024, C = 512, D = 256, U = 256, FU = 1024;
static constexpr int M = Bsz * T;   // 32768 rows for all GEMMs

DEV float bfu2f(unsigned int u) { union { unsigned int i; float f; } v; v.i = u; return v.f; }
DEV unsigned short f2bf(float f) {
    union { float f; unsigned int i; } v; v.f = f;
    return (unsigned short)((v.i + 0x7fffu + ((v.i >> 16) & 1u)) >> 16);
}
DEV float sigmf(float x) { return 1.0f / (1.0f + __expf(-x)); }
DEV float tanhfast(float x) {
    const float a = __expf(-2.0f * fabsf(x));
    const float t = (1.0f - a) / (1.0f + a);
    return copysignf(t, x);
}
DEV float rdlane(float v, int l) {
    return __builtin_bit_cast(float, __builtin_amdgcn_readlane(__builtin_bit_cast(int, v), l));
}
DEV floatx2 bfpair(unsigned int w) {
    floatx2 r; r[0] = bfu2f(w << 16); r[1] = bfu2f(w & 0xffff0000u); return r;
}

// fp32-or-bf16 element -> bf16 bit pattern (GEMM operand loads)
DEV short ld_bf(const float* p) { return (short)f2bf(*p); }
DEV short ld_bf(const unsigned short* p) { return (short)*p; }
DEV short8 ld_frag(const unsigned short* p) { return *(const short8*)p; }
DEV short8 ld_frag(const float* p) {
    short8 v;
#pragma unroll
    for (int j = 0; j < 8; j++) v[j] = (short)f2bf(p[j]);
    return v;
}

// ---------------------------------------------------------------------------
// Fragment-direct MFMA GEMM:  C[M,N] = A[M,K] @ B[K,N] + bias[N]
// One wave/block; wave owns NS 16-col strips (B frags in VGPRs), MT row tiles.
// Layouts (m89/m120-verified): A[m=lane&15][k=quad*8+j];
//   B[k=quad*8+j][n=lane&15]; D[m=quad*4+r][n=lane&15]
// ---------------------------------------------------------------------------
template <int K, int N, int MT, int NS, bool OUTF32, typename AT, typename BT>
__global__ __launch_bounds__(64) void gemm_mfma(
    const AT* __restrict__ A,
    const BT* __restrict__ Bm,
    const float* __restrict__ bias,
    void* __restrict__ Cv)
{
    constexpr int KC = K / 32;
    const int lane = threadIdx.x;
    const int quad = lane >> 4, lr = lane & 15;
    constexpr int NSG = N / (16 * NS);
    const int sg = blockIdx.x % NSG;
    const int mb = blockIdx.x / NSG;
    const int n0 = sg * 16 * NS;

    short8 bf[NS][KC];
    float biasv[NS];
#pragma unroll
    for (int s = 0; s < NS; s++) {
        const int n = n0 + s * 16 + lr;
        biasv[s] = bias[n];
#pragma unroll
        for (int kc = 0; kc < KC; kc++) {
            short8 v;
#pragma unroll
            for (int j = 0; j < 8; j++) {
                const int k = kc * 32 + quad * 8 + j;
                v[j] = ld_bf(&Bm[(size_t)k * N + n]);
            }
            bf[s][kc] = v;
        }
    }

    for (int mt = 0; mt < MT; mt++) {
        const int m0 = (mb * MT + mt) * 16;
        const AT* Ap = A + (size_t)(m0 + lr) * K + quad * 8;
        floatx4 acc[NS];
#pragma unroll
        for (int s = 0; s < NS; s++) acc[s] = (floatx4){0.f, 0.f, 0.f, 0.f};
#pragma unroll
        for (int kc = 0; kc < KC; kc++) {
            short8 af = ld_frag(Ap + kc * 32);
#pragma unroll
            for (int s = 0; s < NS; s++)
                acc[s] = __builtin_amdgcn_mfma_f32_16x16x32_bf16(af, bf[s][kc], acc[s], 0, 0, 0);
        }
#pragma unroll
        for (int s = 0; s < NS; s++) {
            const int n = n0 + s * 16 + lr;
#pragma unroll
            for (int r = 0; r < 4; r++) {
                const int m = m0 + quad * 4 + r;
                const float val = acc[s][r] + biasv[s];
                if (OUTF32)
                    ((float*)Cv)[(size_t)m * N + n] = val;
                else
                    ((unsigned short*)Cv)[(size_t)m * N + n] = f2bf(val);
            }
        }
    }
}

// ---------------------------------------------------------------------------
// Pack rec_kernel fp32 [256][1024] -> P[chunk=64][colpair=512][4 rows] uint4.
// P[(c*512+t)*4 + r] = bf16pair( W[4c+r][2t], W[4c+r][2t+1] ).
// ---------------------------------------------------------------------------
__global__ __launch_bounds__(256) void pack_rec(const float* __restrict__ rec,
                                                uint4* __restrict__ P)
{
    const int i = blockIdx.x * 256 + threadIdx.x;    // [0, 64*512)
    const int c = i >> 9, t = i & 511;
    uint4 v;
    unsigned int* vp = (unsigned int*)&v;
#pragma unroll
    for (int r = 0; r < 4; r++) {
        const int row = 4 * c + r;
        const float lo = rec[(size_t)row * FU + 2 * t];
        const float hi = rec[(size_t)row * FU + 2 * t + 1];
        vp[r] = (unsigned int)f2bf(lo) | ((unsigned int)f2bf(hi) << 16);
    }
    P[i] = v;
}

// ---------------------------------------------------------------------------
// LSTM: one WG (512 threads) per batch. Thread owns cols 2t,2t+1 of the
// [256 -> 1024] rec matmul. W streamed from L2 as 64 coalesced dwordx4/step
// with a 4-deep prefetch ring; h broadcast via v_readlane (lane c holds
// h[4c..4c+3]); z as float2 (pk_fma). Gate order (Keras): i, f, g, o.
// ---------------------------------------------------------------------------
DEV floatx2 ldxz2(const float* p) {
    const float2 v = *(const float2*)p;
    floatx2 r; r[0] = v.x; r[1] = v.y; return r;
}
DEV floatx2 ldxz2(const unsigned short* p) {
    return bfpair(*(const unsigned int*)p);
}

template <typename XZT>
__global__ __launch_bounds__(512) void lstm_kernel(
    const XZT* __restrict__ xz,            // [B, T, 4U]
    const uint4* __restrict__ Wp,          // packed rec, 64*512 uint4
    unsigned short* __restrict__ hs)       // [B, T, U] bf16 out
{
    const int b = blockIdx.x;
    const int tid = threadIdx.x;
    const int lane = tid & 63;
    const int c0 = tid * 2;
    const int off = (blockIdx.x & 7) << 3;   // XCD stagger: desync L2 hotspots
    __shared__ __align__(16) float h_sh[U];
    __shared__ float z_sh[FU];
    float c = 0.f;
    if (tid < U) h_sh[tid] = 0.f;
    __syncthreads();

    const XZT* xzb = xz + (size_t)b * T * FU;
    unsigned short* hsb = hs + (size_t)b * T * U;

    floatx2 xznext = ldxz2(xzb + c0);      // prefetch t=0

    for (int t = 0; t < T; t++) {
        floatx2 z = xznext;
        if (t + 1 < T) xznext = ldxz2(xzb + (size_t)(t + 1) * FU + c0);

        const float4 hr = *(const float4*)&h_sh[lane * 4];

        uint4 buf[4];
#pragma unroll
        for (int i = 0; i < 4; i++)
            buf[i] = Wp[(((i + off) & 63) << 9) + tid];

#pragma unroll
        for (int ch = 0; ch < 64; ch++) {
            const int cc = (ch + off) & 63;
            const uint4 w = buf[ch & 3];
            if (ch + 4 < 64)
                buf[ch & 3] = Wp[(((ch + 4 + off) & 63) << 9) + tid];
            const float a0 = rdlane(hr.x, cc);
            const float a1 = rdlane(hr.y, cc);
            const float a2 = rdlane(hr.z, cc);
            const float a3 = rdlane(hr.w, cc);
            z += (floatx2){a0, a0} * bfpair(w.x);
            z += (floatx2){a1, a1} * bfpair(w.y);
            z += (floatx2){a2, a2} * bfpair(w.z);
            z += (floatx2){a3, a3} * bfpair(w.w);
        }
        z_sh[c0] = z[0];
        z_sh[c0 + 1] = z[1];
        __syncthreads();
        if (tid < U) {
            const float iv = sigmf(z_sh[tid]);
            const float fv = sigmf(z_sh[tid + U]);
            const float gv = tanhfast(z_sh[tid + 2 * U]);
            const float ov = sigmf(z_sh[tid + 3 * U]);
            c = fv * c + iv * gv;
            const float hv = ov * tanhfast(c);
            h_sh[tid] = hv;
            hsb[(size_t)t * U + tid] = f2bf(hv);
        }
        __syncthreads();
    }
}

// ---------------------------------------------------------------------------
extern "C" void kernel_launch(void* const* d_in, const int* in_sizes, int n_in,
                              void* d_out, int out_size, void* d_ws, size_t ws_size,
                              hipStream_t stream)
{
    const float* x    = (const float*)d_in[0];
    const float* w_in = (const float*)d_in[1];
    const float* b_in = (const float*)d_in[2];
    const float* kern = (const float*)d_in[3];
    const float* rec  = (const float*)d_in[4];
    const float* bias = (const float*)d_in[5];
    const float* wout = (const float*)d_in[6];
    const float* bout = (const float*)d_in[7];

    char* ws = (char*)d_ws;
    const size_t rec_bytes = (size_t)U * FU * 2;          // 512 KiB packed W
    const size_t xin_bytes = (size_t)M * D * 2;           // 16 MiB
    const size_t hs_bytes  = (size_t)M * U * 2;           // 16 MiB
    const size_t xz32_bytes = (size_t)M * FU * 4;         // 128 MiB
    const size_t base = rec_bytes + xin_bytes + hs_bytes;

    uint4* Wp = (uint4*)ws;
    unsigned short* xin_bf = (unsigned short*)(ws + rec_bytes);
    unsigned short* hs_bf  = (unsigned short*)(ws + rec_bytes + xin_bytes);
    char* xz_raw = ws + base;

    const bool use_f32 = ws_size >= base + xz32_bytes;

    // pack rec_kernel -> bf16 tiled layout (every launch; ws is re-poisoned)
    pack_rec<<<(64 * 512) / 256, 256, 0, stream>>>(rec, Wp);

    // GEMM1: xin = bf16(x @ w_in + b_in)   [M,512]x[512,256]
    gemm_mfma<512, 256, 16, 2, false><<<(256 / 32) * (M / 256), 64, 0, stream>>>(
        x, w_in, b_in, (void*)xin_bf);

    if (use_f32) {
        float* xz = (float*)xz_raw;
        // GEMM2: xz = fp32(xin @ kernel + bias)  [M,256]x[256,1024]
        gemm_mfma<256, 1024, 16, 2, true><<<(1024 / 32) * (M / 256), 64, 0, stream>>>(
            xin_bf, kern, bias, (void*)xz);
        lstm_kernel<float><<<Bsz, 512, 0, stream>>>(xz, Wp, hs_bf);
    } else {
        unsigned short* xz = (unsigned short*)xz_raw;
        gemm_mfma<256, 1024, 16, 2, false><<<(1024 / 32) * (M / 256), 64, 0, stream>>>(
            xin_bf, kern, bias, (void*)xz);
        lstm_kernel<unsigned short><<<Bsz, 512, 0, stream>>>(xz, Wp, hs_bf);
    }

    // GEMM3: out = fp32(hs @ w_out + b_out)  [M,256]x[256,256]
    gemm_mfma<256, 256, 16, 2, true><<<(256 / 32) * (M / 256), 64, 0, stream>>>(
        hs_bf, wout, bout, d_out);
}

// Round 4
// 4271.634 us; speedup vs baseline: 4.8079x; 4.0678x over previous
//
#include <hip/hip_runtime.h>

// ---------------------------------------------------------------------------
// RNN_Layer: x[B,T,C] fp32 -> conv1x1(w_in) -> dense(kernel) -> LSTM(rec)
//            -> dense(w_out).  B=32 T=1024 C=512 D=256 U=256 O=256.
// R4 LSTM: register-resident weights. 1 WG (1024 thr, 16 waves) per batch;
// thread owns one of 1024 gate-columns. W (f16 k-pair packed, 256 KB... 512KB
// as 128 uint/col) split: 96 uints in VGPRs (384 KB/WG), 32 streamed from L2
// (128 KB/step, 4-deep). MACs via v_dot2_f32_f16 (2 MAC/op, no unpack);
// h broadcast with v_readlane of f16-pairs staged in LDS (ds_read_b64/lane).
// Per-step model: max(VALU ~2320 cyc, L2 ~2048 cyc) + gates -> ~1.3us/step.
// ---------------------------------------------------------------------------

#define DEV static __device__ __forceinline__

typedef __attribute__((ext_vector_type(8))) short short8;
typedef __attribute__((ext_vector_type(4))) float floatx4;
typedef _Float16 half2v __attribute__((ext_vector_type(2)));

static constexpr int Bsz = 32, T = 1024, C = 512, D = 256, U = 256, FU = 1024;
static constexpr int M = Bsz * T;   // 32768 rows for all GEMMs

DEV float bfu2f(unsigned int u) { union { unsigned int i; float f; } v; v.i = u; return v.f; }
DEV float bf2f(unsigned short u) { return bfu2f(((unsigned int)u) << 16); }
DEV unsigned short f2bf(float f) {
    union { float f; unsigned int i; } v; v.f = f;
    return (unsigned short)((v.i + 0x7fffu + ((v.i >> 16) & 1u)) >> 16);
}
DEV float sigmf(float x) { return 1.0f / (1.0f + __expf(-x)); }
DEV float tanhfast(float x) {
    const float a = __expf(-2.0f * fabsf(x));
    const float t = (1.0f - a) / (1.0f + a);
    return copysignf(t, x);
}

// 2-way f16 dot with fp32 accumulate: z += w.lo*a.lo + w.hi*a.hi
DEV float dot2h(unsigned int w, unsigned int a, float acc) {
#if __has_builtin(__builtin_amdgcn_fdot2)
    return __builtin_amdgcn_fdot2(__builtin_bit_cast(half2v, w),
                                  __builtin_bit_cast(half2v, a), acc, false);
#else
    const half2v wv = __builtin_bit_cast(half2v, w);
    const half2v av = __builtin_bit_cast(half2v, a);
    return acc + (float)wv[0] * (float)av[0] + (float)wv[1] * (float)av[1];
#endif
}

// fp32-or-bf16 element -> bf16 bit pattern (GEMM operand loads)
DEV short ld_bf(const float* p) { return (short)f2bf(*p); }
DEV short ld_bf(const unsigned short* p) { return (short)*p; }
DEV short8 ld_frag(const unsigned short* p) { return *(const short8*)p; }
DEV short8 ld_frag(const float* p) {
    short8 v;
#pragma unroll
    for (int j = 0; j < 8; j++) v[j] = (short)f2bf(p[j]);
    return v;
}
DEV float ldxz1(const float* p) { return *p; }
DEV float ldxz1(const unsigned short* p) { return bf2f(*p); }

// ---------------------------------------------------------------------------
// Fragment-direct MFMA GEMM:  C[M,N] = A[M,K] @ B[K,N] + bias[N]
// One wave/block; wave owns NS 16-col strips (B frags in VGPRs), MT row tiles.
// Layouts (m89/m120-verified): A[m=lane&15][k=quad*8+j];
//   B[k=quad*8+j][n=lane&15]; D[m=quad*4+r][n=lane&15]
// ---------------------------------------------------------------------------
template <int K, int N, int MT, int NS, bool OUTF32, typename AT, typename BT>
__global__ __launch_bounds__(64) void gemm_mfma(
    const AT* __restrict__ A,
    const BT* __restrict__ Bm,
    const float* __restrict__ bias,
    void* __restrict__ Cv)
{
    constexpr int KC = K / 32;
    const int lane = threadIdx.x;
    const int quad = lane >> 4, lr = lane & 15;
    constexpr int NSG = N / (16 * NS);
    const int sg = blockIdx.x % NSG;
    const int mb = blockIdx.x / NSG;
    const int n0 = sg * 16 * NS;

    short8 bf[NS][KC];
    float biasv[NS];
#pragma unroll
    for (int s = 0; s < NS; s++) {
        const int n = n0 + s * 16 + lr;
        biasv[s] = bias[n];
#pragma unroll
        for (int kc = 0; kc < KC; kc++) {
            short8 v;
#pragma unroll
            for (int j = 0; j < 8; j++) {
                const int k = kc * 32 + quad * 8 + j;
                v[j] = ld_bf(&Bm[(size_t)k * N + n]);
            }
            bf[s][kc] = v;
        }
    }

    for (int mt = 0; mt < MT; mt++) {
        const int m0 = (mb * MT + mt) * 16;
        const AT* Ap = A + (size_t)(m0 + lr) * K + quad * 8;
        floatx4 acc[NS];
#pragma unroll
        for (int s = 0; s < NS; s++) acc[s] = (floatx4){0.f, 0.f, 0.f, 0.f};
#pragma unroll
        for (int kc = 0; kc < KC; kc++) {
            short8 af = ld_frag(Ap + kc * 32);
#pragma unroll
            for (int s = 0; s < NS; s++)
                acc[s] = __builtin_amdgcn_mfma_f32_16x16x32_bf16(af, bf[s][kc], acc[s], 0, 0, 0);
        }
#pragma unroll
        for (int s = 0; s < NS; s++) {
            const int n = n0 + s * 16 + lr;
#pragma unroll
            for (int r = 0; r < 4; r++) {
                const int m = m0 + quad * 4 + r;
                const float val = acc[s][r] + biasv[s];
                if (OUTF32)
                    ((float*)Cv)[(size_t)m * N + n] = val;
                else
                    ((unsigned short*)Cv)[(size_t)m * N + n] = f2bf(val);
            }
        }
    }
}

// ---------------------------------------------------------------------------
// Pack rec_kernel fp32 [256][1024] -> P[32][1024] uint4 of f16 k-pairs.
// P[g][c].r = pack_f16( W[8g+2r][c], W[8g+2r+1][c] ); kpair kk=4g+r covers
// rows 2kk,2kk+1 of column c.
// ---------------------------------------------------------------------------
__global__ __launch_bounds__(256) void pack_rec(const float* __restrict__ rec,
                                                uint4* __restrict__ P)
{
    const int i = blockIdx.x * 256 + threadIdx.x;    // [0, 32*1024)
    const int g = i >> 10, c = i & 1023;
    uint4 v;
    unsigned int* vp = (unsigned int*)&v;
#pragma unroll
    for (int r = 0; r < 4; r++) {
        const _Float16 lo = (_Float16)rec[(size_t)(8 * g + 2 * r) * FU + c];
        const _Float16 hi = (_Float16)rec[(size_t)(8 * g + 2 * r + 1) * FU + c];
        vp[r] = (unsigned int)__builtin_bit_cast(unsigned short, lo)
              | ((unsigned int)__builtin_bit_cast(unsigned short, hi) << 16);
    }
    P[i] = v;
}

// ---------------------------------------------------------------------------
// LSTM. 1 WG (1024 threads) per batch; thread c owns gate-column c.
//   z[c] = xz[t][c] + sum_k h[k]*W[k][c], via 128 f16 k-pair dot2s.
//   W kpairs 0..95 live in VGPRs (wr[24] uint4); kpairs 96..127 stream from
//   L2 each step (8 uint4/thread, <=4 live). h kept as f16 pairs in LDS;
//   each lane holds h[4l..4l+3] (one b64), broadcast by v_readlane.
// Gate order (Keras): i, f, g, o.  Cell state fp32 in thread c<256.
// ---------------------------------------------------------------------------
template <typename XZT>
__global__ __launch_bounds__(1024, 4) void lstm_kernel(
    const XZT* __restrict__ xz,            // [B, T, 4U]
    const uint4* __restrict__ P,           // packed rec, [32][1024] uint4
    unsigned short* __restrict__ hs)       // [B, T, U] bf16 out
{
    const int b = blockIdx.x;
    const int c = threadIdx.x;
    const int lane = c & 63;
    __shared__ float z_sh[FU];
    __shared__ unsigned short h_pk[U];     // f16 bits of h

    float cst = 0.f;
    if (c < U) h_pk[c] = 0;
    __syncthreads();

    const XZT* xzb = xz + (size_t)b * T * FU;
    unsigned short* hsb = hs + (size_t)b * T * U;
    const uint4* Pc = P + c;

    // resident W: kpairs 0..95 (rows 0..191), 96 VGPRs
    uint4 wr[24];
#pragma unroll
    for (int g = 0; g < 24; g++) wr[g] = Pc[g * 1024];

    float xznext = ldxz1(xzb + c);

#define DO_KP(kk, w) { \
        const unsigned int a_ = (unsigned int)__builtin_amdgcn_readlane( \
            (int)(((kk) & 1) ? hp.y : hp.x), (kk) >> 1); \
        z = dot2h((w), a_, z); }

    for (int t = 0; t < T; t++) {
        float z = xznext;
        // stream part of W: kpairs 96..127, 4-deep
        uint4 s0 = Pc[24 * 1024];
        uint4 s1 = Pc[25 * 1024];
        uint4 s2 = Pc[26 * 1024];
        uint4 s3 = Pc[27 * 1024];
        if (t + 1 < T) xznext = ldxz1(xzb + (size_t)(t + 1) * FU + c);

        const uint2 hp = *(const uint2*)&h_pk[lane * 4];   // h[4l..4l+3] f16

#pragma unroll
        for (int g = 0; g < 12; g++) {                     // kpairs 0..47
#pragma unroll
            for (int r = 0; r < 4; r++) DO_KP(4 * g + r, wr[g][r]);
        }
#pragma unroll
        for (int r = 0; r < 4; r++) DO_KP(96 + r, s0[r]);  // 96..99
#pragma unroll
        for (int r = 0; r < 4; r++) DO_KP(100 + r, s1[r]); // 100..103
        s0 = Pc[28 * 1024];
        s1 = Pc[29 * 1024];
#pragma unroll
        for (int g = 12; g < 20; g++) {                    // kpairs 48..79
#pragma unroll
            for (int r = 0; r < 4; r++) DO_KP(4 * g + r, wr[g][r]);
        }
#pragma unroll
        for (int r = 0; r < 4; r++) DO_KP(104 + r, s2[r]); // 104..107
#pragma unroll
        for (int r = 0; r < 4; r++) DO_KP(108 + r, s3[r]); // 108..111
        s2 = Pc[30 * 1024];
        s3 = Pc[31 * 1024];
#pragma unroll
        for (int g = 20; g < 24; g++) {                    // kpairs 80..95
#pragma unroll
            for (int r = 0; r < 4; r++) DO_KP(4 * g + r, wr[g][r]);
        }
#pragma unroll
        for (int r = 0; r < 4; r++) DO_KP(112 + r, s0[r]); // 112..115
#pragma unroll
        for (int r = 0; r < 4; r++) DO_KP(116 + r, s1[r]); // 116..119
#pragma unroll
        for (int r = 0; r < 4; r++) DO_KP(120 + r, s2[r]); // 120..123
#pragma unroll
        for (int r = 0; r < 4; r++) DO_KP(124 + r, s3[r]); // 124..127

        z_sh[c] = z;
        __syncthreads();
        if (c < U) {
            const float iv = sigmf(z_sh[c]);
            const float fv = sigmf(z_sh[c + U]);
            const float gv = tanhfast(z_sh[c + 2 * U]);
            const float ov = sigmf(z_sh[c + 3 * U]);
            cst = fv * cst + iv * gv;
            const float hv = ov * tanhfast(cst);
            h_pk[c] = __builtin_bit_cast(unsigned short, (_Float16)hv);
            hsb[(size_t)t * U + c] = f2bf(hv);
        }
        __syncthreads();
    }
#undef DO_KP
}

// ---------------------------------------------------------------------------
extern "C" void kernel_launch(void* const* d_in, const int* in_sizes, int n_in,
                              void* d_out, int out_size, void* d_ws, size_t ws_size,
                              hipStream_t stream)
{
    const float* x    = (const float*)d_in[0];
    const float* w_in = (const float*)d_in[1];
    const float* b_in = (const float*)d_in[2];
    const float* kern = (const float*)d_in[3];
    const float* rec  = (const float*)d_in[4];
    const float* bias = (const float*)d_in[5];
    const float* wout = (const float*)d_in[6];
    const float* bout = (const float*)d_in[7];

    char* ws = (char*)d_ws;
    const size_t rec_bytes = (size_t)32 * 1024 * 16;      // 512 KiB packed W
    const size_t xin_bytes = (size_t)M * D * 2;           // 16 MiB
    const size_t hs_bytes  = (size_t)M * U * 2;           // 16 MiB
    const size_t xz32_bytes = (size_t)M * FU * 4;         // 128 MiB
    const size_t base = rec_bytes + xin_bytes + hs_bytes;

    uint4* P = (uint4*)ws;
    unsigned short* xin_bf = (unsigned short*)(ws + rec_bytes);
    unsigned short* hs_bf  = (unsigned short*)(ws + rec_bytes + xin_bytes);
    char* xz_raw = ws + base;

    const bool use_f32 = ws_size >= base + xz32_bytes;

    // pack rec_kernel -> f16 k-pair tiled layout (every launch; ws re-poisoned)
    pack_rec<<<(32 * 1024) / 256, 256, 0, stream>>>(rec, P);

    // GEMM1: xin = bf16(x @ w_in + b_in)   [M,512]x[512,256]
    gemm_mfma<512, 256, 16, 2, false><<<(256 / 32) * (M / 256), 64, 0, stream>>>(
        x, w_in, b_in, (void*)xin_bf);

    if (use_f32) {
        float* xz = (float*)xz_raw;
        // GEMM2: xz = fp32(xin @ kernel + bias)  [M,256]x[256,1024]
        gemm_mfma<256, 1024, 16, 2, true><<<(1024 / 32) * (M / 256), 64, 0, stream>>>(
            xin_bf, kern, bias, (void*)xz);
        lstm_kernel<float><<<Bsz, 1024, 0, stream>>>(xz, P, hs_bf);
    } else {
        unsigned short* xz = (unsigned short*)xz_raw;
        gemm_mfma<256, 1024, 16, 2, false><<<(1024 / 32) * (M / 256), 64, 0, stream>>>(
            xin_bf, kern, bias, (void*)xz);
        lstm_kernel<unsigned short><<<Bsz, 1024, 0, stream>>>(xz, P, hs_bf);
    }

    // GEMM3: out = fp32(hs @ w_out + b_out)  [M,256]x[256,256]
    gemm_mfma<256, 256, 16, 2, true><<<(256 / 32) * (M / 256), 64, 0, stream>>>(
        hs_bf, wout, bout, d_out);
}